// Round 7
// baseline (39.993 us; speedup 1.0000x reference)
//
#include <hip/hip_runtime.h>

// SlidingPosBiases3D: out[(h,w,d),(h',w',d')] = biases[h'-h+R, w'-w+R, d'-d+R]
// if all relative offsets lie in [0, 2R], else 0.  H=W=D=20, R=7 fixed by setup.
//
// Work item = (row-group g, vec-column v): 4 consecutive rows (same h,w;
// d = 4g%20 .. +3) x one float4 column chunk. 7 bias loads feed 4 float4
// stores (value depends only on k - r). Bias table (13.5 KB) read through L1
// (R6: no LDS staging). Plain stores (R3: nontemporal cost ~17% BW).
// R7: per-block CONTIGUOUS item range [b*NITEMS/2048, (b+1)*NITEMS/2048):
// every block does identical 1953.125-item work -> perfect per-CU balance
// (grid-stride gave blocks 7 vs 8 passes -> ~1.6% tail), and each block's
// stores cover one contiguous ~125 KB region.

constexpr int R  = 7;
constexpr int S1 = 2 * R + 1;      // 15

constexpr int H = 20, W = 20, D = 20;
constexpr int N = H * W * D;       // 8000
constexpr int NV = N / 4;          // 2000 float4 per row
constexpr int RPB = 4;             // rows per group (divides D)
constexpr int NGRP = N / RPB;      // 2000 row-groups
constexpr long long NITEMS = (long long)NGRP * NV;   // 4,000,000
constexpr int NBLK = 2048;         // 8 blocks/CU exactly (2^11 for exact shift)
constexpr int NTHR = 256;

__global__ __launch_bounds__(NTHR)
void SlidingPosBiases3D_kernel(const float* __restrict__ biases,
                               float* __restrict__ out) {
    const int start = (int)((NITEMS * blockIdx.x) >> 11);        // b*1953.125
    const int end   = (int)((NITEMS * (blockIdx.x + 1)) >> 11);

    for (int idx = start + threadIdx.x; idx < end; idx += NTHR) {
        const int g = idx / NV;            // row-group (magic div)
        const int v = idx - g * NV;        // vec column

        const int row0  = g * RPB;
        const int dbase = row0 % D;        // rows have d = dbase + r, r<4
        const int hw    = row0 / D;
        const int w     = hw % W;
        const int h     = hw / W;

        const int col = v * 4;
        const int d0  = col % D;           // 0,4,...,16 (4 | D)
        const int rem = col / D;
        const int wp  = rem % W;
        const int hp  = rem / W;

        const int ih = hp - h + R;
        const int iw = wp - w + R;
        const bool ok = ((unsigned)ih < (unsigned)S1) & ((unsigned)iw < (unsigned)S1);
        const int base = ih * (S1 * S1) + iw * S1;
        const int e    = d0 - dbase + R;   // id for (row r, elem k) = e + k - r

        float t[7];                        // t[j] = bias at id = e-3+j (masked)
        #pragma unroll
        for (int j = 0; j < 7; ++j) {
            const int id = e - 3 + j;
            const bool m = ok & ((unsigned)id < (unsigned)S1);
            int idc = id < 0 ? 0 : (id > S1 - 1 ? S1 - 1 : id);
            const int addr = ok ? base + idc : 0;   // always in-bounds
            t[j] = m ? biases[addr] : 0.f; // L1-resident (13.5 KB table)
        }

        float* __restrict__ obase = out + (size_t)row0 * N;
        #pragma unroll
        for (int r = 0; r < RPB; ++r) {
            float4 val = make_float4(t[3 - r], t[4 - r], t[5 - r], t[6 - r]);
            *((float4*)(obase + (size_t)r * N) + v) = val;
        }
    }
}

extern "C" void kernel_launch(void* const* d_in, const int* in_sizes, int n_in,
                              void* d_out, int out_size, void* d_ws, size_t ws_size,
                              hipStream_t stream) {
    const float* biases = (const float*)d_in[0];
    float* out = (float*)d_out;
    SlidingPosBiases3D_kernel<<<NBLK, NTHR, 0, stream>>>(biases, out);
}

// Round 8
// 39.384 us; speedup vs baseline: 1.0154x; 1.0154x over previous
//
#include <hip/hip_runtime.h>

// SlidingPosBiases3D: out[(h,w,d),(h',w',d')] = biases[h'-h+R, w'-w+R, d'-d+R]
// if all relative offsets lie in [0, 2R], else 0.  H=W=D=20, R=7 fixed by setup.
//
// Final (R6 variant — measured best, 39.44 us = 6.49 TB/s write BW, 91% of
// this machine's memset rate; output is 256 MB write-only so this is the
// practical roofline):
//  - Work item = (row-group g, vec-column v): 4 consecutive rows (same h,w;
//    d = 4g%20..+3) x one float4 column chunk. 7 bias loads feed 4 float4
//    stores (value depends only on k - r).
//  - Bias table (13.5 KB) read directly through L1 — no LDS staging/preamble.
//  - Plain stores (R3 A/B: nontemporal stores cost ~17% BW — bypass L2
//    write aggregation on gfx950).
//  - Grid-stride over 4M items, 2048 blocks (8/CU) x 256 threads.
//  - R7 contiguous-range split was neutral-to-worse (reverted).

constexpr int R  = 7;
constexpr int S1 = 2 * R + 1;      // 15

constexpr int H = 20, W = 20, D = 20;
constexpr int N = H * W * D;       // 8000
constexpr int NV = N / 4;          // 2000 float4 per row
constexpr int RPB = 4;             // rows per group (divides D)
constexpr int NGRP = N / RPB;      // 2000 row-groups
constexpr long long NITEMS = (long long)NGRP * NV;   // 4,000,000
constexpr int NBLK = 2048;         // 8 blocks/CU exactly
constexpr int NTHR = 256;

__global__ __launch_bounds__(NTHR)
void SlidingPosBiases3D_kernel(const float* __restrict__ biases,
                               float* __restrict__ out) {
    for (int idx = blockIdx.x * NTHR + threadIdx.x; idx < (int)NITEMS;
         idx += NBLK * NTHR) {
        const int g = idx / NV;            // row-group (magic div)
        const int v = idx - g * NV;        // vec column

        const int row0  = g * RPB;
        const int dbase = row0 % D;        // rows have d = dbase + r, r<4
        const int hw    = row0 / D;
        const int w     = hw % W;
        const int h     = hw / W;

        const int col = v * 4;
        const int d0  = col % D;           // 0,4,...,16 (4 | D)
        const int rem = col / D;
        const int wp  = rem % W;
        const int hp  = rem / W;

        const int ih = hp - h + R;
        const int iw = wp - w + R;
        const bool ok = ((unsigned)ih < (unsigned)S1) & ((unsigned)iw < (unsigned)S1);
        const int base = ih * (S1 * S1) + iw * S1;
        const int e    = d0 - dbase + R;   // id for (row r, elem k) = e + k - r

        float t[7];                        // t[j] = bias at id = e-3+j (masked)
        #pragma unroll
        for (int j = 0; j < 7; ++j) {
            const int id = e - 3 + j;
            const bool m = ok & ((unsigned)id < (unsigned)S1);
            int idc = id < 0 ? 0 : (id > S1 - 1 ? S1 - 1 : id);
            const int addr = ok ? base + idc : 0;   // always in-bounds
            t[j] = m ? biases[addr] : 0.f; // L1-resident (13.5 KB table)
        }

        float* __restrict__ obase = out + (size_t)row0 * N;
        #pragma unroll
        for (int r = 0; r < RPB; ++r) {
            float4 val = make_float4(t[3 - r], t[4 - r], t[5 - r], t[6 - r]);
            *((float4*)(obase + (size_t)r * N) + v) = val;
        }
    }
}

extern "C" void kernel_launch(void* const* d_in, const int* in_sizes, int n_in,
                              void* d_out, int out_size, void* d_ws, size_t ws_size,
                              hipStream_t stream) {
    const float* biases = (const float*)d_in[0];
    float* out = (float*)d_out;
    SlidingPosBiases3D_kernel<<<NBLK, NTHR, 0, stream>>>(biases, out);
}